// Round 8
// baseline (467.734 us; speedup 1.0000x reference)
//
#include <hip/hip_runtime.h>

#define N_NODES 50000
#define N_EDGES 800000
#define DIM 256
#define HEADS 8
#define NEG_SLOPE 0.2f

typedef unsigned short u16;
typedef float floatx4 __attribute__((ext_vector_type(4)));
typedef __bf16 bf16x8 __attribute__((ext_vector_type(8)));

__device__ __forceinline__ float b2f(u16 u) {
    union { unsigned int i; float f; } v; v.i = ((unsigned int)u) << 16; return v.f;
}
__device__ __forceinline__ u16 f2b(float f) {
    union { float f; unsigned int i; } v; v.f = f;
    unsigned int x = v.i;
    unsigned int r = (x + 0x7fffu + ((x >> 16) & 1u)) >> 16;
    return (u16)r;
}

__global__ __launch_bounds__(256) void fill_u32(unsigned int* __restrict__ p,
                                                unsigned int v, int n) {
    int i = blockIdx.x * 256 + threadIdx.x;
    if (i < n) p[i] = v;
}

// ---- init: zero counts; block 0 detects dtype ----
__global__ __launch_bounds__(256) void init_kernel(const unsigned int* __restrict__ d,
                                                   int* __restrict__ counts,
                                                   int* __restrict__ flag) {
    int i = blockIdx.x * 256 + threadIdx.x;
    if (i < N_NODES) counts[i] = 0;
    if (blockIdx.x == 0) {
        __shared__ int cnt;
        if (threadIdx.x == 0) cnt = 0;
        __syncthreads();
        unsigned int w = d[threadIdx.x];
        int bad = 0;
        #pragma unroll
        for (int half = 0; half < 2; ++half) {
            u16 u = (u16)(w >> (16 * half));
            unsigned int e = (u >> 7) & 0xFFu;
            if (u != 0 && (e >= 141u || e <= 27u)) bad = 1;
        }
        atomicAdd(&cnt, bad);
        __syncthreads();
        if (threadIdx.x == 0) *flag = (cnt > 64) ? 1 : 0;   // 1 = fp32 inputs
    }
}

// ---- prep: blocks 0..31 W transpose->bf16; 32/33 alr = W-FOLDED al/ar ----
// alr[col][k] = sum_d W[k][32h+d] * a[h][d]  (h=col&7; a=al if col<8 else ar)
// so that el = (x@W)·al == x @ alr_col  computed by the GEMM-epilogue MFMA.
__global__ __launch_bounds__(256) void prep_kernel(const void* __restrict__ W1,
                                                   const void* __restrict__ W2,
                                                   const void* __restrict__ al1,
                                                   const void* __restrict__ ar1,
                                                   const void* __restrict__ al2,
                                                   const void* __restrict__ ar2,
                                                   u16* __restrict__ Wt1,
                                                   u16* __restrict__ Wt2,
                                                   u16* __restrict__ alr1,
                                                   u16* __restrict__ alr2,
                                                   const int* __restrict__ flagp) {
    const int isf = *flagp;
    int b = blockIdx.x;
    if (b < 32) {
        const void* W = (b < 16) ? W1 : W2;
        u16* Wt = (b < 16) ? Wt1 : Wt2;
        int t = b & 15;
        int k0 = (t >> 2) * 64, n0 = (t & 3) * 64;
        __shared__ float lt[64][65];
        int c = threadIdx.x & 63, r0 = threadIdx.x >> 6;
        #pragma unroll
        for (int j = 0; j < 16; ++j) {
            int r = j * 4 + r0;
            lt[r][c] = isf ? ((const float*)W)[(k0 + r) * 256 + n0 + c]
                           : b2f(((const u16*)W)[(k0 + r) * 256 + n0 + c]);
        }
        __syncthreads();
        #pragma unroll
        for (int j = 0; j < 16; ++j) {
            int rn = j * 4 + r0;
            Wt[(n0 + rn) * 256 + k0 + c] = f2b(lt[c][rn]);   // Wt[n][k]=W[k][n]
        }
    } else {
        const void* W  = (b == 32) ? W1 : W2;
        const void* al = (b == 32) ? al1 : al2;
        const void* ar = (b == 32) ? ar1 : ar2;
        u16* alr = (b == 32) ? alr1 : alr2;
        for (int idx = threadIdx.x; idx < 4096; idx += 256) {
            int col = idx >> 8, k = idx & 255;
            int h = col & 7;
            const void* a = (col < 8) ? al : ar;
            float s = 0.f;
            #pragma unroll 8
            for (int d = 0; d < 32; ++d) {
                float wv = isf ? ((const float*)W)[k * 256 + h * 32 + d]
                               : b2f(((const u16*)W)[k * 256 + h * 32 + d]);
                float av = isf ? ((const float*)a)[h * 32 + d]
                               : b2f(((const u16*)a)[h * 32 + d]);
                s += wv * av;
            }
            alr[col * 256 + k] = f2b(s);
        }
    }
}

// ---------------- CSR build ----------------
__global__ __launch_bounds__(256) void hist_kernel(const int* __restrict__ dst,
                                                   int* __restrict__ counts, int E) {
    int i = blockIdx.x * 256 + threadIdx.x;
    if (i < E) atomicAdd(&counts[dst[i]], 1);
}

__global__ __launch_bounds__(256) void scan_partial(const int* __restrict__ counts,
                                                    int* __restrict__ partial, int n) {
    int b = blockIdx.x, tid = threadIdx.x;
    int base = b * 1024 + tid * 4;
    int s = 0;
    #pragma unroll
    for (int k = 0; k < 4; ++k) if (base + k < n) s += counts[base + k];
    int lane = tid & 63;
    #pragma unroll
    for (int off = 32; off; off >>= 1) s += __shfl_xor(s, off);
    __shared__ int wsum[4];
    if (lane == 0) wsum[tid >> 6] = s;
    __syncthreads();
    if (tid == 0) partial[b] = wsum[0] + wsum[1] + wsum[2] + wsum[3];
}

// scan_write with inline cross-block offset reduction (nb <= 64)
__global__ __launch_bounds__(256) void scan_write(const int* __restrict__ counts,
                                                  const int* __restrict__ partial,
                                                  int* __restrict__ row_ptr,
                                                  int* __restrict__ wptr, int n, int nb) {
    int b = blockIdx.x, tid = threadIdx.x;
    __shared__ int off_s, tot_s;
    if (tid < 64) {
        int pv = (tid < nb) ? partial[tid] : 0;
        int vb = (tid < b) ? pv : 0;
        int vt = pv;
        #pragma unroll
        for (int m = 32; m; m >>= 1) { vb += __shfl_xor(vb, m); vt += __shfl_xor(vt, m); }
        if (tid == 0) { off_s = vb; tot_s = vt; }
    }
    __syncthreads();
    int base = b * 1024 + tid * 4;
    int v[4]; int s = 0;
    #pragma unroll
    for (int k = 0; k < 4; ++k) { v[k] = (base + k < n) ? counts[base + k] : 0; s += v[k]; }
    int lane = tid & 63, w = tid >> 6;
    int incl = s;
    #pragma unroll
    for (int d = 1; d < 64; d <<= 1) {
        int u = __shfl_up(incl, d);
        if (lane >= d) incl += u;
    }
    __shared__ int wsum[4];
    if (lane == 63) wsum[w] = incl;
    __syncthreads();
    int woff = 0;
    for (int i = 0; i < w; ++i) woff += wsum[i];
    int run = off_s + woff + incl - s;
    #pragma unroll
    for (int k = 0; k < 4; ++k) {
        if (base + k < n) { row_ptr[base + k] = run; wptr[base + k] = run; run += v[k]; }
    }
    if (b == 0 && tid == 0) row_ptr[n] = tot_s;
}

__global__ __launch_bounds__(256) void scatter_kernel(const int* __restrict__ src,
                                                      const int* __restrict__ dst,
                                                      int* __restrict__ wptr,
                                                      int* __restrict__ src_sorted, int E) {
    int i = blockIdx.x * 256 + threadIdx.x;
    if (i < E) {
        int pos = atomicAdd(&wptr[dst[i]], 1);
        src_sorted[pos] = src[i];
    }
}

// ---- GEMM: barrier-free K-loop, B global->VGPR, el/er via MFMA vs folded alr ----
#define LDA 264

__global__ __launch_bounds__(256, 3) void gemm_fused(const void* __restrict__ A,
                                                     const u16* __restrict__ Wt,
                                                     const u16* __restrict__ alr,
                                                     u16* __restrict__ outF,
                                                     float* __restrict__ el,
                                                     float* __restrict__ er,
                                                     int M, int a_fp32_if_isf,
                                                     const int* __restrict__ flagp) {
    __shared__ u16 As[64][LDA];
    const int tid  = threadIdx.x;
    const int w    = tid >> 6;       // wave: n-quarter
    const int lane = tid & 63;
    const int quad = lane >> 4;
    const int l16  = lane & 15;
    const int m0   = blockIdx.x * 64;
    const bool a_fp32 = a_fp32_if_isf && (*flagp != 0);

    // stage A tile (single barrier)
    #pragma unroll
    for (int it = 0; it < 8; ++it) {
        int idx = it * 256 + tid;
        int r = idx >> 5;
        int c = (idx & 31) << 3;
        int gr = m0 + r;
        if (gr < M) {
            if (a_fp32) {
                const float* Af = (const float*)A;
                float4 f0 = *(const float4*)(Af + gr * 256 + c);
                float4 f1 = *(const float4*)(Af + gr * 256 + c + 4);
                u16 tb[8] = {f2b(f0.x), f2b(f0.y), f2b(f0.z), f2b(f0.w),
                             f2b(f1.x), f2b(f1.y), f2b(f1.z), f2b(f1.w)};
                *(uint4*)&As[r][c] = *(uint4*)tb;
            } else {
                *(uint4*)&As[r][c] = *(const uint4*)((const u16*)A + gr * 256 + c);
            }
        } else {
            uint4 z = {0u, 0u, 0u, 0u};
            *(uint4*)&As[r][c] = z;
        }
    }
    __syncthreads();

    floatx4 acc[4][4] = {};
    floatx4 eacc[4] = {};

    const u16* Wb = Wt + (64 * w + l16) * 256 + quad * 8;   // + 16t*256 + 32s
    const u16* Eb = alr + l16 * 256 + quad * 8;

    #pragma unroll
    for (int s = 0; s < 8; ++s) {
        bf16x8 bfv[4], ebf;
        #pragma unroll
        for (int t = 0; t < 4; ++t)
            bfv[t] = *(const bf16x8*)(Wb + t * 16 * 256 + s * 32);
        ebf = *(const bf16x8*)(Eb + s * 32);
        bf16x8 af[4];
        #pragma unroll
        for (int i = 0; i < 4; ++i)
            af[i] = *(const bf16x8*)&As[16 * i + l16][s * 32 + quad * 8];
        #pragma unroll
        for (int i = 0; i < 4; ++i) {
            #pragma unroll
            for (int t = 0; t < 4; ++t)
                acc[i][t] = __builtin_amdgcn_mfma_f32_16x16x32_bf16(af[i], bfv[t], acc[i][t], 0, 0, 0);
            eacc[i] = __builtin_amdgcn_mfma_f32_16x16x32_bf16(af[i], ebf, eacc[i], 0, 0, 0);
        }
    }

    // C-writes: col = l16, row = quad*4+r
    #pragma unroll
    for (int i = 0; i < 4; ++i)
        #pragma unroll
        for (int t = 0; t < 4; ++t)
            #pragma unroll
            for (int r = 0; r < 4; ++r) {
                int row = m0 + 16 * i + quad * 4 + r;
                if (row < M) outF[row * 256 + 64 * w + 16 * t + l16] = f2b(acc[i][t][r]);
            }
    // el/er identical across waves (same A-tile, same alr); wave 0 stores.
    if (w == 0) {
        #pragma unroll
        for (int i = 0; i < 4; ++i)
            #pragma unroll
            for (int r = 0; r < 4; ++r) {
                int row = m0 + 16 * i + quad * 4 + r;
                if (row < M) {
                    float v = eacc[i][r];
                    if (l16 < 8) el[row * 8 + l16] = v;
                    else         er[row * 8 + (l16 - 8)] = v;
                }
            }
    }
}

// ---- aggregate: 1 wave/node, online softmax, hoisted-shfl 4-deep row sweep ----
__global__ __launch_bounds__(256) void aggregate_kernel(const u16* __restrict__ feat,
                                                        const float* __restrict__ el,
                                                        const float* __restrict__ er,
                                                        const void* __restrict__ bias,
                                                        const int* __restrict__ row_ptr,
                                                        const int* __restrict__ src_sorted,
                                                        void* __restrict__ out,
                                                        int out_mode,
                                                        const int* __restrict__ flagp) {
    const int isf = *flagp;
    const int lane = threadIdx.x & 63;
    const int node = blockIdx.x * 4 + (threadIdx.x >> 6);
    if (node >= N_NODES) return;
    const int h = lane >> 3;
    const int j = lane & 7;
    const int beg = row_ptr[node];
    const int deg = row_ptr[node + 1] - beg;
    const float ern = er[node * HEADS + h];

    // online softmax (8 lanes stride this head's edges)
    float m = -1e30f, ssum = 0.f;
    for (int i = j; i < deg; i += 8) {
        int s = src_sorted[beg + i];
        float e = el[s * 8 + h] + ern;
        e = e > 0.f ? e : NEG_SLOPE * e;
        float mn = fmaxf(m, e);
        ssum = ssum * __expf(m - mn) + __expf(e - mn);
        m = mn;
    }
    #pragma unroll
    for (int mask = 1; mask <= 4; mask <<= 1) {
        float mo = __shfl_xor(m, mask);
        float so = __shfl_xor(ssum, mask);
        float mn = fmaxf(m, mo);
        ssum = ssum * __expf(m - mn) + so * __expf(mo - mn);
        m = mn;
    }
    const float mx = m;
    const float inv = ssum > 0.f ? 1.f / ssum : 0.f;

    // phase 2: each half-wave sweeps 4 of 8 chunk edges, full 256-dim rows
    const int q = lane & 31;       // owns dims 8q..8q+7
    const int half = lane >> 5;
    const int hq = q >> 2;
    float a[8] = {};

    const int full = deg & ~7;
    int c0 = 0;
    for (; c0 < full; c0 += 8) {
        int i = c0 + j;
        int s = src_sorted[beg + i];
        float e = el[s * 8 + h] + ern;
        e = e > 0.f ? e : NEG_SLOPE * e;
        float av = __expf(e - mx) * inv;
        int se[4]; float ae[4];
        #pragma unroll
        for (int k = 0; k < 4; ++k) {
            int sel = hq * 8 + 2 * k + half;
            se[k] = __shfl(s, sel);
            ae[k] = __shfl(av, sel);
        }
        #pragma unroll
        for (int k = 0; k < 4; ++k) {
            uint4 f = *(const uint4*)(feat + se[k] * DIM + 8 * q);
            float w = ae[k];
            a[0] += w * b2f((u16)(f.x & 0xffffu)); a[1] += w * b2f((u16)(f.x >> 16));
            a[2] += w * b2f((u16)(f.y & 0xffffu)); a[3] += w * b2f((u16)(f.y >> 16));
            a[4] += w * b2f((u16)(f.z & 0xffffu)); a[5] += w * b2f((u16)(f.z >> 16));
            a[6] += w * b2f((u16)(f.w & 0xffffu)); a[7] += w * b2f((u16)(f.w >> 16));
        }
    }
    if (c0 < deg) {   // tail chunk
        int i = c0 + j;
        int s = 0; float av = 0.f;
        if (i < deg) {
            s = src_sorted[beg + i];
            float e = el[s * 8 + h] + ern;
            e = e > 0.f ? e : NEG_SLOPE * e;
            av = __expf(e - mx) * inv;
        }
        int rem = deg - c0;
        int se[4]; float ae[4];
        #pragma unroll
        for (int k = 0; k < 4; ++k) {
            int sel = hq * 8 + 2 * k + half;
            se[k] = __shfl(s, sel);
            ae[k] = __shfl(av, sel);
        }
        #pragma unroll
        for (int k = 0; k < 4; ++k) {
            if (2 * k + half < rem) {
                uint4 f = *(const uint4*)(feat + se[k] * DIM + 8 * q);
                float w = ae[k];
                a[0] += w * b2f((u16)(f.x & 0xffffu)); a[1] += w * b2f((u16)(f.x >> 16));
                a[2] += w * b2f((u16)(f.y & 0xffffu)); a[3] += w * b2f((u16)(f.y >> 16));
                a[4] += w * b2f((u16)(f.z & 0xffffu)); a[5] += w * b2f((u16)(f.z >> 16));
                a[6] += w * b2f((u16)(f.w & 0xffffu)); a[7] += w * b2f((u16)(f.w >> 16));
            }
        }
    }
    #pragma unroll
    for (int k = 0; k < 8; ++k) a[k] += __shfl_xor(a[k], 32);

    if (half == 0) {
        float o[8];
        if (isf) {
            float4 b0 = *(const float4*)((const float*)bias + 8 * q);
            float4 b1 = *(const float4*)((const float*)bias + 8 * q + 4);
            o[0] = a[0] + b0.x; o[1] = a[1] + b0.y; o[2] = a[2] + b0.z; o[3] = a[3] + b0.w;
            o[4] = a[4] + b1.x; o[5] = a[5] + b1.y; o[6] = a[6] + b1.z; o[7] = a[7] + b1.w;
        } else {
            uint4 bu = *(const uint4*)((const u16*)bias + 8 * q);
            o[0] = a[0] + b2f((u16)(bu.x & 0xffffu)); o[1] = a[1] + b2f((u16)(bu.x >> 16));
            o[2] = a[2] + b2f((u16)(bu.y & 0xffffu)); o[3] = a[3] + b2f((u16)(bu.y >> 16));
            o[4] = a[4] + b2f((u16)(bu.z & 0xffffu)); o[5] = a[5] + b2f((u16)(bu.z >> 16));
            o[6] = a[6] + b2f((u16)(bu.w & 0xffffu)); o[7] = a[7] + b2f((u16)(bu.w >> 16));
        }
        #pragma unroll
        for (int k = 0; k < 8; ++k) o[k] = fmaxf(o[k], 0.f);
        if (out_mode == 0 || !isf) {
            u16 pk[8] = {f2b(o[0]), f2b(o[1]), f2b(o[2]), f2b(o[3]),
                         f2b(o[4]), f2b(o[5]), f2b(o[6]), f2b(o[7])};
            *(uint4*)((u16*)out + node * DIM + 8 * q) = *(uint4*)pk;
        } else {
            float4 v0 = {o[0], o[1], o[2], o[3]};
            float4 v1 = {o[4], o[5], o[6], o[7]};
            *(float4*)((float*)out + node * DIM + 8 * q) = v0;
            *(float4*)((float*)out + node * DIM + 8 * q + 4) = v1;
        }
    }
}

// ---------------- launch ----------------
extern "C" void kernel_launch(void* const* d_in, const int* in_sizes, int n_in,
                              void* d_out, int out_size, void* d_ws, size_t ws_size,
                              hipStream_t stream) {
    const void* data = d_in[0];
    const int* src = (const int*)d_in[1];
    const int* dst = (const int*)d_in[2];
    const void* W1  = d_in[3];
    const void* al1 = d_in[4];
    const void* ar1 = d_in[5];
    const void* b1  = d_in[6];
    const void* W2  = d_in[7];
    const void* al2 = d_in[8];
    const void* ar2 = d_in[9];
    const void* b2  = d_in[10];

    const size_t NEEDED =
        (size_t)N_NODES * DIM * 2 +        // feat
        (size_t)N_NODES * HEADS * 4 * 2 +  // el, er
        (size_t)N_NODES * 4 * 2 +          // counts, wptr
        (size_t)(N_NODES + 4) * 4 +        // row_ptr
        (size_t)N_EDGES * 4 +              // src_sorted
        2 * 256 * 256 * 2 +                // Wt1, Wt2
        2 * 16 * 256 * 2 +                 // alr1, alr2
        1024;

    if (ws_size < NEEDED) {
        int nwords = (out_size + 1) / 2;
        fill_u32<<<(nwords + 255) / 256, 256, 0, stream>>>(
            (unsigned int*)d_out, 0x42C842C8u, nwords);
        return;
    }

    char* ws = (char*)d_ws;
    u16* feat = (u16*)ws;        ws += (size_t)N_NODES * DIM * 2;
    float* el = (float*)ws;      ws += (size_t)N_NODES * HEADS * 4;
    float* er = (float*)ws;      ws += (size_t)N_NODES * HEADS * 4;
    int* counts = (int*)ws;      ws += (size_t)N_NODES * 4;
    int* wptr = (int*)ws;        ws += (size_t)N_NODES * 4;
    int* row_ptr = (int*)ws;     ws += (size_t)(N_NODES + 4) * 4;
    int* src_sorted = (int*)ws;  ws += (size_t)N_EDGES * 4;
    u16* Wt1 = (u16*)ws;         ws += 256 * 256 * 2;
    u16* Wt2 = (u16*)ws;         ws += 256 * 256 * 2;
    u16* alr1 = (u16*)ws;        ws += 16 * 256 * 2;
    u16* alr2 = (u16*)ws;        ws += 16 * 256 * 2;
    int* partial = (int*)ws;     ws += 256;
    int* flag = (int*)ws;        ws += 256;

    u16* h1 = (u16*)d_out;       // layer-1 acts (bf16) parked in d_out

    const int nb = (N_NODES + 1023) / 1024;   // 49

    init_kernel<<<(N_NODES + 255) / 256, 256, 0, stream>>>(
        (const unsigned int*)data, counts, flag);
    prep_kernel<<<34, 256, 0, stream>>>(W1, W2, al1, ar1, al2, ar2,
                                        Wt1, Wt2, alr1, alr2, flag);
    hist_kernel<<<(N_EDGES + 255) / 256, 256, 0, stream>>>(dst, counts, N_EDGES);
    scan_partial<<<nb, 256, 0, stream>>>(counts, partial, N_NODES);
    scan_write<<<nb, 256, 0, stream>>>(counts, partial, row_ptr, wptr, N_NODES, nb);
    scatter_kernel<<<(N_EDGES + 255) / 256, 256, 0, stream>>>(src, dst, wptr, src_sorted, N_EDGES);

    const int gemm_blocks = (N_NODES + 63) / 64;
    const int agg_blocks = (N_NODES + 3) / 4;

    gemm_fused<<<gemm_blocks, 256, 0, stream>>>(data, Wt1, alr1, feat, el, er,
                                                N_NODES, 1, flag);
    aggregate_kernel<<<agg_blocks, 256, 0, stream>>>(feat, el, er, b1, row_ptr, src_sorted,
                                                     (void*)h1, 0, flag);
    gemm_fused<<<gemm_blocks, 256, 0, stream>>>(h1, Wt2, alr2, feat, el, er,
                                                N_NODES, 0, flag);
    aggregate_kernel<<<agg_blocks, 256, 0, stream>>>(feat, el, er, b2, row_ptr, src_sorted,
                                                     d_out, 2, flag);
}